// Round 2
// baseline (406.077 us; speedup 1.0000x reference)
//
#include <hip/hip_runtime.h>

#define NUM_HEADS 8

__device__ __forceinline__ float2 cmul(float2 a, float2 b) {
    return make_float2(a.x*b.x - a.y*b.y, a.x*b.y + a.y*b.x);
}

// ---- K_pre: P[n][l*8+h] = feat[n] . W[l][h]
// W[l][h] pair_d = 0.25 * (w2[h] pair_d) x conj(frv[l][d]);  W[3][h] += w1[h]
// Lane j = l*8+h holds W[j] (32 float2) in registers; features staged in LDS,
// consumed as conflict-free broadcast reads.
__global__ __launch_bounds__(256) void k_pre(
    const float4* __restrict__ feat4,   // N*16 float4
    const float2* __restrict__ rvec,
    const float2* __restrict__ w1_g,
    const float2* __restrict__ w2_g,
    float*        __restrict__ P, int N)
{
    __shared__ float4 sf[1024];         // 64 nodes x 16 float4 = 16 KB
    int tid = threadIdx.x;
    int lane = tid & 31;
    int l = lane >> 3, h = lane & 7;

    float2 Wr[32];
    for (int d = 0; d < 32; ++d) {
        float2 a = rvec[d], b = rvec[32 + d];
        float na = rsqrtf(a.x*a.x + a.y*a.y); a.x *= na; a.y *= na;
        float nb = rsqrtf(b.x*b.x + b.y*b.y); b.x *= nb; b.y *= nb;
        // ETYPES=[0,2,1]: fr3=1, fr2=conj(rv0), fr1=fr2*rv1, fr0=fr1*rv0
        float2 fr2 = make_float2(a.x, -a.y);
        float2 fr1 = cmul(fr2, b);
        float2 fr0 = cmul(fr1, a);
        float2 fr = (l == 0) ? fr0 : (l == 1) ? fr1 : (l == 2) ? fr2 : make_float2(1.f, 0.f);
        float2 frc = make_float2(fr.x, -fr.y);         // conj(frv[l])
        float2 w2 = w2_g[h*32 + d];
        float2 wl = cmul(w2, frc);
        wl.x *= 0.25f; wl.y *= 0.25f;
        if (l == 3) { float2 w1 = w1_g[h*32 + d]; wl.x += w1.x; wl.y += w1.y; }
        Wr[d] = wl;
    }

    int n0 = blockIdx.x * 64;
    int lim = (N - n0) * 16;            // float4s valid in this tile
    for (int i = tid; i < 1024; i += 256)
        sf[i] = (i < lim) ? feat4[(size_t)n0 * 16 + i] : make_float4(0.f, 0.f, 0.f, 0.f);
    __syncthreads();

    int grp = tid >> 5;
    #pragma unroll
    for (int k = 0; k < 8; ++k) {
        int n = n0 + grp * 8 + k;
        if (n >= N) break;
        const float4* fp = &sf[(grp * 8 + k) * 16];
        float acc = 0.f;
        #pragma unroll
        for (int q = 0; q < 16; ++q) {
            float4 v = fp[q];           // same addr across lanes -> LDS broadcast
            acc += v.x * Wr[2*q].x + v.y * Wr[2*q].y
                 + v.z * Wr[2*q+1].x + v.w * Wr[2*q+1].y;
        }
        P[(size_t)n * 32 + lane] = acc;
    }
}

// ---- K_count: degree histogram ----
__global__ void k_count(const int* __restrict__ edge_dst, int* __restrict__ counts, int E) {
    int e = blockIdx.x * 256 + threadIdx.x;
    if (e < E) atomicAdd(&counts[edge_dst[e]], 1);
}

// ---- K2a: per-tile (1024) exclusive scan; tile sums out ----
__global__ __launch_bounds__(256) void k_scan_a(
    const int* __restrict__ counts, int* __restrict__ offsets,
    int* __restrict__ blocksums, int N)
{
    __shared__ int s[256];
    int t = threadIdx.x;
    int base = blockIdx.x * 1024 + t * 4;
    int v0 = (base     < N) ? counts[base]     : 0;
    int v1 = (base + 1 < N) ? counts[base + 1] : 0;
    int v2 = (base + 2 < N) ? counts[base + 2] : 0;
    int v3 = (base + 3 < N) ? counts[base + 3] : 0;
    s[t] = v0 + v1 + v2 + v3;
    __syncthreads();
    #pragma unroll
    for (int off = 1; off < 256; off <<= 1) {
        int x = (t >= off) ? s[t - off] : 0;
        __syncthreads();
        s[t] += x;
        __syncthreads();
    }
    if (t == 255) blocksums[blockIdx.x] = s[255];
    int run = (t == 0) ? 0 : s[t - 1];
    if (base     < N) offsets[base]     = run; run += v0;
    if (base + 1 < N) offsets[base + 1] = run; run += v1;
    if (base + 2 < N) offsets[base + 2] = run; run += v2;
    if (base + 3 < N) offsets[base + 3] = run;
}

// ---- K2b: exclusive scan of tile sums (B <= 1024), one block ----
__global__ __launch_bounds__(1024) void k_scan_b(
    int* __restrict__ blocksums, int* __restrict__ total, int B)
{
    __shared__ int s[1024];
    int t = threadIdx.x;
    s[t] = (t < B) ? blocksums[t] : 0;
    __syncthreads();
    #pragma unroll
    for (int off = 1; off < 1024; off <<= 1) {
        int x = (t >= off) ? s[t - off] : 0;
        __syncthreads();
        s[t] += x;
        __syncthreads();
    }
    if (t < B) blocksums[t] = (t == 0) ? 0 : s[t - 1];
    if (t == 1023) *total = s[1023];   // == E
}

// ---- K2c: add tile prefix; emit cursor copy and offsets[N] ----
__global__ __launch_bounds__(256) void k_scan_c(
    int* __restrict__ offsets, int* __restrict__ cursor,
    const int* __restrict__ blocksums, const int* __restrict__ total, int N)
{
    int i = blockIdx.x * 256 + threadIdx.x;
    if (i < N) {
        int v = offsets[i] + blocksums[i >> 10];
        offsets[i] = v;
        cursor[i] = v;
    }
    if (i == 0) offsets[N] = *total;
}

// ---- K_edge: per-edge hidden + exp-weights, written at dst-sorted position.
// Row layout (36 float2 = 288 B): [32 x float2 hidden | 8 x float exp(leaky(a))]
__global__ __launch_bounds__(256) void k_edge(
    const float2* __restrict__ feat,
    const float2* __restrict__ rvec,
    const float*  __restrict__ P,
    const int4*   __restrict__ emi,
    const int*    __restrict__ edge_dst,
    int*          __restrict__ cursor,
    float2*       __restrict__ hbuf,    // E rows of 36 float2
    int E)
{
    __shared__ float2 s_frv[96];
    int tid = threadIdx.x;
    if (tid < 32) {
        float2 a = rvec[tid], b = rvec[32 + tid];
        float na = rsqrtf(a.x*a.x + a.y*a.y); a.x *= na; a.y *= na;
        float nb = rsqrtf(b.x*b.x + b.y*b.y); b.x *= nb; b.y *= nb;
        float2 fr2 = make_float2(a.x, -a.y);
        float2 fr1 = cmul(fr2, b);
        float2 fr0 = cmul(fr1, a);
        s_frv[tid] = fr0; s_frv[32 + tid] = fr1; s_frv[64 + tid] = fr2;
    }
    __syncthreads();

    int e = blockIdx.x * 8 + (tid >> 5);
    if (e >= E) return;
    int lane = tid & 31;

    int4 idx = emi[e];
    int pos = 0;
    if (lane == 0) pos = atomicAdd(&cursor[edge_dst[e]], 1);
    pos = __shfl(pos, 0, 32);

    float2 f0 = feat[(size_t)idx.x * 32 + lane];
    float2 f1 = feat[(size_t)idx.y * 32 + lane];
    float2 f2 = feat[(size_t)idx.z * 32 + lane];
    float2 c3 = feat[(size_t)idx.w * 32 + lane];
    float2 fr0 = s_frv[lane], fr1 = s_frv[32 + lane], fr2 = s_frv[64 + lane];

    float2 hv;
    hv.x = c3.x + f0.x*fr0.x - f0.y*fr0.y
                + f1.x*fr1.x - f1.y*fr1.y
                + f2.x*fr2.x - f2.y*fr2.y;
    hv.y = c3.y + f0.x*fr0.y + f0.y*fr0.x
                + f1.x*fr1.y + f1.y*fr1.x
                + f2.x*fr2.y + f2.y*fr2.x;
    hv.x *= 0.25f; hv.y *= 0.25f;

    float2* row = hbuf + (size_t)pos * 36;
    row[lane] = hv;

    if (lane < NUM_HEADS) {
        float a = P[(size_t)idx.x * 32 + lane]
                + P[(size_t)idx.y * 32 +  8 + lane]
                + P[(size_t)idx.z * 32 + 16 + lane]
                + P[(size_t)idx.w * 32 + 24 + lane];
        a = a > 0.f ? a : 0.01f * a;            // LeakyReLU
        ((float*)(row + 32))[lane] = __expf(a); // no max-sub: |a| small, exp bounded
    }
}

// ---- K_out: pure streaming per-node softmax-normalize + aggregate ----
__global__ __launch_bounds__(256) void k_out(
    const float2* __restrict__ hbuf,
    const int*    __restrict__ offsets,
    float2*       __restrict__ out,      // (N,8,64) f32 = N*8*32 float2
    int N)
{
    int tid = threadIdx.x;
    int n = blockIdx.x * 8 + (tid >> 5);
    if (n >= N) return;
    int lane = tid & 31;
    int beg = offsets[n], end = offsets[n + 1];

    if (beg == end) {   // isolated node: segment_sum over empty set = 0
        float2 z = make_float2(0.f, 0.f);
        #pragma unroll
        for (int hh = 0; hh < NUM_HEADS; ++hh)
            out[((size_t)n * 8 + hh) * 32 + lane] = z;
        return;
    }

    float dsum[NUM_HEADS];
    float2 acc[NUM_HEADS];
    #pragma unroll
    for (int hh = 0; hh < NUM_HEADS; ++hh) { dsum[hh] = 0.f; acc[hh] = make_float2(0.f, 0.f); }

    for (int j = beg; j < end; ++j) {
        const float2* row = hbuf + (size_t)j * 36;
        float2 hv = row[lane];
        float4 wa = ((const float4*)(row + 32))[0];  // broadcast
        float4 wb = ((const float4*)(row + 32))[1];
        dsum[0] += wa.x; acc[0].x += wa.x * hv.x; acc[0].y += wa.x * hv.y;
        dsum[1] += wa.y; acc[1].x += wa.y * hv.x; acc[1].y += wa.y * hv.y;
        dsum[2] += wa.z; acc[2].x += wa.z * hv.x; acc[2].y += wa.z * hv.y;
        dsum[3] += wa.w; acc[3].x += wa.w * hv.x; acc[3].y += wa.w * hv.y;
        dsum[4] += wb.x; acc[4].x += wb.x * hv.x; acc[4].y += wb.x * hv.y;
        dsum[5] += wb.y; acc[5].x += wb.y * hv.x; acc[5].y += wb.y * hv.y;
        dsum[6] += wb.z; acc[6].x += wb.z * hv.x; acc[6].y += wb.z * hv.y;
        dsum[7] += wb.w; acc[7].x += wb.w * hv.x; acc[7].y += wb.w * hv.y;
    }

    #pragma unroll
    for (int hh = 0; hh < NUM_HEADS; ++hh) {
        float r = 1.f / dsum[hh];
        out[((size_t)n * 8 + hh) * 32 + lane] = make_float2(acc[hh].x * r, acc[hh].y * r);
    }
}

extern "C" void kernel_launch(void* const* d_in, const int* in_sizes, int n_in,
                              void* d_out, int out_size, void* d_ws, size_t ws_size,
                              hipStream_t stream) {
    const float2* feat = (const float2*)d_in[0];   // features f32 (N,64)
    const float2* rvec = (const float2*)d_in[1];   // r_vec f32 (2,32,2)
    const float2* w1   = (const float2*)d_in[2];   // attn1_w f32 (8,64)
    const float2* w2   = (const float2*)d_in[3];   // attn2 f32 (1,8,64)
    const int4*   emi  = (const int4*)d_in[4];     // (E,4) int32
    const int* edge_dst = (const int*)d_in[5];     // (E,) int32

    int N = in_sizes[0] / 64;
    int E = in_sizes[4] / 4;
    int nTiles = (N + 1023) / 1024;                // N=100k -> 98 (<=1024)

    char* w = (char*)d_ws;
    float*  P        = (float*)w;                  // N*32 f32 (12.8 MB)
    float2* hbuf     = (float2*)(P + (size_t)N * 32);  // E*36 float2 (72 MB)
    int*    counts   = (int*)(hbuf + (size_t)E * 36);  // N
    int*    offsets  = counts + N;                 // N+1
    int*    cursor   = offsets + N + 1;            // N
    int*    blocksums= cursor + N;                 // nTiles (pad 1024)
    int*    total    = blocksums + 1024;           // 1

    hipMemsetAsync(counts, 0, (size_t)N * 4, stream);

    k_count<<<(E + 255) / 256, 256, 0, stream>>>(edge_dst, counts, E);
    k_pre<<<(N + 63) / 64, 256, 0, stream>>>((const float4*)feat, rvec, w1, w2, P, N);
    k_scan_a<<<nTiles, 256, 0, stream>>>(counts, offsets, blocksums, N);
    k_scan_b<<<1, 1024, 0, stream>>>(blocksums, total, nTiles);
    k_scan_c<<<(N + 255) / 256, 256, 0, stream>>>(offsets, cursor, blocksums, total, N);
    k_edge<<<(E + 7) / 8, 256, 0, stream>>>(feat, rvec, P, emi, edge_dst, cursor,
                                            hbuf, E);
    k_out<<<(N + 7) / 8, 256, 0, stream>>>(hbuf, offsets, (float2*)d_out, N);
}

// Round 5
// 382.930 us; speedup vs baseline: 1.0604x; 1.0604x over previous
//
#include <hip/hip_runtime.h>

#define NUM_HEADS 8

typedef float f2 __attribute__((ext_vector_type(2)));

__device__ __forceinline__ float2 cmul(float2 a, float2 b) {
    return make_float2(a.x*b.x - a.y*b.y, a.x*b.y + a.y*b.x);
}

__device__ __forceinline__ void nt_store2(float2* p, float x, float y) {
    f2 v; v.x = x; v.y = y;
    __builtin_nontemporal_store(v, (f2*)p);
}

// ---- K_pre: P[n][l*8+h] = feat[n] . W[l][h]
// W[l][h] pair_d = 0.25 * (w2[h] pair_d) x conj(frv[l][d]);  W[3][h] += w1[h]
// Lane j = l*8+h holds W[j] (32 float2) in registers; features staged in LDS,
// consumed as conflict-free broadcast reads.
__global__ __launch_bounds__(256) void k_pre(
    const float4* __restrict__ feat4,   // N*16 float4
    const float2* __restrict__ rvec,
    const float2* __restrict__ w1_g,
    const float2* __restrict__ w2_g,
    float*        __restrict__ P, int N)
{
    __shared__ float4 sf[1024];         // 64 nodes x 16 float4 = 16 KB
    int tid = threadIdx.x;
    int lane = tid & 31;
    int l = lane >> 3, h = lane & 7;

    float2 Wr[32];
    for (int d = 0; d < 32; ++d) {
        float2 a = rvec[d], b = rvec[32 + d];
        float na = rsqrtf(a.x*a.x + a.y*a.y); a.x *= na; a.y *= na;
        float nb = rsqrtf(b.x*b.x + b.y*b.y); b.x *= nb; b.y *= nb;
        // ETYPES=[0,2,1]: fr3=1, fr2=conj(rv0), fr1=fr2*rv1, fr0=fr1*rv0
        float2 fr2 = make_float2(a.x, -a.y);
        float2 fr1 = cmul(fr2, b);
        float2 fr0 = cmul(fr1, a);
        float2 fr = (l == 0) ? fr0 : (l == 1) ? fr1 : (l == 2) ? fr2 : make_float2(1.f, 0.f);
        float2 frc = make_float2(fr.x, -fr.y);         // conj(frv[l])
        float2 w2 = w2_g[h*32 + d];
        float2 wl = cmul(w2, frc);
        wl.x *= 0.25f; wl.y *= 0.25f;
        if (l == 3) { float2 w1 = w1_g[h*32 + d]; wl.x += w1.x; wl.y += w1.y; }
        Wr[d] = wl;
    }

    int n0 = blockIdx.x * 64;
    int lim = (N - n0) * 16;            // float4s valid in this tile
    for (int i = tid; i < 1024; i += 256)
        sf[i] = (i < lim) ? feat4[(size_t)n0 * 16 + i] : make_float4(0.f, 0.f, 0.f, 0.f);
    __syncthreads();

    int grp = tid >> 5;
    #pragma unroll
    for (int k = 0; k < 8; ++k) {
        int n = n0 + grp * 8 + k;
        if (n >= N) break;
        const float4* fp = &sf[(grp * 8 + k) * 16];
        float acc = 0.f;
        #pragma unroll
        for (int q = 0; q < 16; ++q) {
            float4 v = fp[q];           // same addr across lanes -> LDS broadcast
            acc += v.x * Wr[2*q].x + v.y * Wr[2*q].y
                 + v.z * Wr[2*q+1].x + v.w * Wr[2*q+1].y;
        }
        P[(size_t)n * 32 + lane] = acc;
    }
}

// ---- K_count: degree histogram ----
__global__ void k_count(const int* __restrict__ edge_dst, int* __restrict__ counts, int E) {
    int e = blockIdx.x * 256 + threadIdx.x;
    if (e < E) atomicAdd(&counts[edge_dst[e]], 1);
}

// ---- K2a: per-tile (1024) exclusive scan; tile sums out ----
__global__ __launch_bounds__(256) void k_scan_a(
    const int* __restrict__ counts, int* __restrict__ offsets,
    int* __restrict__ blocksums, int N)
{
    __shared__ int s[256];
    int t = threadIdx.x;
    int base = blockIdx.x * 1024 + t * 4;
    int v0 = (base     < N) ? counts[base]     : 0;
    int v1 = (base + 1 < N) ? counts[base + 1] : 0;
    int v2 = (base + 2 < N) ? counts[base + 2] : 0;
    int v3 = (base + 3 < N) ? counts[base + 3] : 0;
    s[t] = v0 + v1 + v2 + v3;
    __syncthreads();
    #pragma unroll
    for (int off = 1; off < 256; off <<= 1) {
        int x = (t >= off) ? s[t - off] : 0;
        __syncthreads();
        s[t] += x;
        __syncthreads();
    }
    if (t == 255) blocksums[blockIdx.x] = s[255];
    int run = (t == 0) ? 0 : s[t - 1];
    if (base     < N) offsets[base]     = run; run += v0;
    if (base + 1 < N) offsets[base + 1] = run; run += v1;
    if (base + 2 < N) offsets[base + 2] = run; run += v2;
    if (base + 3 < N) offsets[base + 3] = run;
}

// ---- K2b: exclusive scan of tile sums (B <= 1024), one block ----
__global__ __launch_bounds__(1024) void k_scan_b(
    int* __restrict__ blocksums, int* __restrict__ total, int B)
{
    __shared__ int s[1024];
    int t = threadIdx.x;
    s[t] = (t < B) ? blocksums[t] : 0;
    __syncthreads();
    #pragma unroll
    for (int off = 1; off < 1024; off <<= 1) {
        int x = (t >= off) ? s[t - off] : 0;
        __syncthreads();
        s[t] += x;
        __syncthreads();
    }
    if (t < B) blocksums[t] = (t == 0) ? 0 : s[t - 1];
    if (t == 1023) *total = s[1023];   // == E
}

// ---- K2c: add tile prefix; emit cursor copy and offsets[N] ----
__global__ __launch_bounds__(256) void k_scan_c(
    int* __restrict__ offsets, int* __restrict__ cursor,
    const int* __restrict__ blocksums, const int* __restrict__ total, int N)
{
    int i = blockIdx.x * 256 + threadIdx.x;
    if (i < N) {
        int v = offsets[i] + blocksums[i >> 10];
        offsets[i] = v;
        cursor[i] = v;
    }
    if (i == 0) offsets[N] = *total;
}

// ---- K3: bucket edge ids by dst ----
__global__ void k_fill(const int* __restrict__ edge_dst, int* __restrict__ cursor,
                       int* __restrict__ edge_ids, int E) {
    int e = blockIdx.x * 256 + threadIdx.x;
    if (e >= E) return;
    int pos = atomicAdd(&cursor[edge_dst[e]], 1);
    edge_ids[pos] = e;
}

// ---- K_edge: per-edge hidden + exp(leaky(logit)) weights, contiguous by e ----
__global__ __launch_bounds__(256) void k_edge(
    const float2* __restrict__ feat,
    const float2* __restrict__ rvec,
    const float*  __restrict__ P,
    const int4*   __restrict__ emi,
    float2*       __restrict__ hidden,  // E*32 float2, row-aligned 256 B
    float*        __restrict__ w_buf,   // E*8 exp-weights, row-aligned 32 B
    int E)
{
    __shared__ float2 s_frv[96];
    int tid = threadIdx.x;
    if (tid < 32) {
        float2 a = rvec[tid], b = rvec[32 + tid];
        float na = rsqrtf(a.x*a.x + a.y*a.y); a.x *= na; a.y *= na;
        float nb = rsqrtf(b.x*b.x + b.y*b.y); b.x *= nb; b.y *= nb;
        float2 fr2 = make_float2(a.x, -a.y);
        float2 fr1 = cmul(fr2, b);
        float2 fr0 = cmul(fr1, a);
        s_frv[tid] = fr0; s_frv[32 + tid] = fr1; s_frv[64 + tid] = fr2;
    }
    __syncthreads();

    int e = blockIdx.x * 8 + (tid >> 5);
    if (e >= E) return;
    int lane = tid & 31;

    int4 idx = emi[e];
    float2 f0 = feat[(size_t)idx.x * 32 + lane];
    float2 f1 = feat[(size_t)idx.y * 32 + lane];
    float2 f2 = feat[(size_t)idx.z * 32 + lane];
    float2 c3 = feat[(size_t)idx.w * 32 + lane];
    float2 fr0 = s_frv[lane], fr1 = s_frv[32 + lane], fr2 = s_frv[64 + lane];

    float2 hv;
    hv.x = c3.x + f0.x*fr0.x - f0.y*fr0.y
                + f1.x*fr1.x - f1.y*fr1.y
                + f2.x*fr2.x - f2.y*fr2.y;
    hv.y = c3.y + f0.x*fr0.y + f0.y*fr0.x
                + f1.x*fr1.y + f1.y*fr1.x
                + f2.x*fr2.y + f2.y*fr2.x;
    hv.x *= 0.25f; hv.y *= 0.25f;
    hidden[(size_t)e * 32 + lane] = hv;

    if (lane < NUM_HEADS) {
        float a = P[(size_t)idx.x * 32 + lane]
                + P[(size_t)idx.y * 32 +  8 + lane]
                + P[(size_t)idx.z * 32 + 16 + lane]
                + P[(size_t)idx.w * 32 + 24 + lane];
        a = a > 0.f ? a : 0.01f * a;            // LeakyReLU
        w_buf[(size_t)e * 8 + lane] = __expf(a); // no max-sub: |a| small, exp bounded
    }
}

// ---- K_out: single-pass per-node normalize + aggregate via edge_ids ----
__global__ __launch_bounds__(256) void k_out(
    const float2* __restrict__ hidden,
    const float*  __restrict__ w_buf,
    const int*    __restrict__ offsets,
    const int*    __restrict__ edge_ids,
    float2*       __restrict__ out,      // (N,8,64) f32 = N*8*32 float2
    int N)
{
    int tid = threadIdx.x;
    int n = blockIdx.x * 8 + (tid >> 5);
    if (n >= N) return;
    int lane = tid & 31;
    int beg = offsets[n], end = offsets[n + 1];

    if (beg == end) {   // isolated node: segment_sum over empty set = 0
        #pragma unroll
        for (int hh = 0; hh < NUM_HEADS; ++hh)
            nt_store2(&out[((size_t)n * 8 + hh) * 32 + lane], 0.f, 0.f);
        return;
    }

    float dsum[NUM_HEADS];
    float2 acc[NUM_HEADS];
    #pragma unroll
    for (int hh = 0; hh < NUM_HEADS; ++hh) { dsum[hh] = 0.f; acc[hh] = make_float2(0.f, 0.f); }

    for (int j = beg; j < end; ++j) {
        int e = edge_ids[j];
        const float4* wp = (const float4*)(w_buf + (size_t)e * 8);
        float4 wa = wp[0], wb = wp[1];           // broadcast across lanes
        float2 hv = hidden[(size_t)e * 32 + lane];
        dsum[0] += wa.x; acc[0].x += wa.x * hv.x; acc[0].y += wa.x * hv.y;
        dsum[1] += wa.y; acc[1].x += wa.y * hv.x; acc[1].y += wa.y * hv.y;
        dsum[2] += wa.z; acc[2].x += wa.z * hv.x; acc[2].y += wa.z * hv.y;
        dsum[3] += wa.w; acc[3].x += wa.w * hv.x; acc[3].y += wa.w * hv.y;
        dsum[4] += wb.x; acc[4].x += wb.x * hv.x; acc[4].y += wb.x * hv.y;
        dsum[5] += wb.y; acc[5].x += wb.y * hv.x; acc[5].y += wb.y * hv.y;
        dsum[6] += wb.z; acc[6].x += wb.z * hv.x; acc[6].y += wb.z * hv.y;
        dsum[7] += wb.w; acc[7].x += wb.w * hv.x; acc[7].y += wb.w * hv.y;
    }

    #pragma unroll
    for (int hh = 0; hh < NUM_HEADS; ++hh) {
        float r = 1.f / dsum[hh];
        nt_store2(&out[((size_t)n * 8 + hh) * 32 + lane], acc[hh].x * r, acc[hh].y * r);
    }
}

extern "C" void kernel_launch(void* const* d_in, const int* in_sizes, int n_in,
                              void* d_out, int out_size, void* d_ws, size_t ws_size,
                              hipStream_t stream) {
    const float2* feat = (const float2*)d_in[0];   // features f32 (N,64)
    const float2* rvec = (const float2*)d_in[1];   // r_vec f32 (2,32,2)
    const float2* w1   = (const float2*)d_in[2];   // attn1_w f32 (8,64)
    const float2* w2   = (const float2*)d_in[3];   // attn2 f32 (1,8,64)
    const int4*   emi  = (const int4*)d_in[4];     // (E,4) int32
    const int* edge_dst = (const int*)d_in[5];     // (E,) int32

    int N = in_sizes[0] / 64;
    int E = in_sizes[4] / 4;
    int nTiles = (N + 1023) / 1024;                // N=100k -> 98 (<=1024)

    char* w = (char*)d_ws;
    float*  P        = (float*)w;                      // N*32 f32 (12.8 MB)
    float*  hidden   = P + (size_t)N * 32;             // E*64 f32 (64 MB)
    float*  w_buf    = hidden + (size_t)E * 64;        // E*8 f32 (8 MB)
    int*    counts   = (int*)(w_buf + (size_t)E * 8);  // N
    int*    offsets  = counts + N;                     // N+1
    int*    cursor   = offsets + N + 1;                // N
    int*    edge_ids = cursor + N;                     // E
    int*    blocksums= edge_ids + E;                   // nTiles (pad 1024)
    int*    total    = blocksums + 1024;               // 1

    (void)hipMemsetAsync(counts, 0, (size_t)N * 4, stream);

    k_count<<<(E + 255) / 256, 256, 0, stream>>>(edge_dst, counts, E);
    k_pre<<<(N + 63) / 64, 256, 0, stream>>>((const float4*)feat, rvec, w1, w2, P, N);
    k_edge<<<(E + 7) / 8, 256, 0, stream>>>(feat, rvec, P, emi,
                                            (float2*)hidden, w_buf, E);
    k_scan_a<<<nTiles, 256, 0, stream>>>(counts, offsets, blocksums, N);
    k_scan_b<<<1, 1024, 0, stream>>>(blocksums, total, nTiles);
    k_scan_c<<<(N + 255) / 256, 256, 0, stream>>>(offsets, cursor, blocksums, total, N);
    k_fill<<<(E + 255) / 256, 256, 0, stream>>>(edge_dst, cursor, edge_ids, E);
    k_out<<<(N + 7) / 8, 256, 0, stream>>>((const float2*)hidden, w_buf,
                                           offsets, edge_ids, (float2*)d_out, N);
}